// Round 10
// baseline (148.870 us; speedup 1.0000x reference)
//
#include <hip/hip_runtime.h>
#include <hip/hip_bf16.h>
#include <stdint.h>

#define NB 4096
#define ND 1024

typedef __attribute__((ext_vector_type(8))) short bf16x8;
typedef __attribute__((ext_vector_type(4))) float f32x4;

// ---------------------------------------------------------------------------
// prep: row-normalize to bf16 (wave per row, no block barriers), pack label key
// ---------------------------------------------------------------------------
__global__ __launch_bounds__(256) void prep_kernel(
    const float* __restrict__ emb, const int* __restrict__ labels,
    unsigned short* __restrict__ z, int* __restrict__ keys)
{
    const int wid = threadIdx.x >> 6, lane = threadIdx.x & 63;
    const int row = blockIdx.x * 4 + wid;
    const float4* src = (const float4*)(emb + (size_t)row * ND);
    float4 v[4];
    float ss = 0.0f;
    #pragma unroll
    for (int j = 0; j < 4; ++j) {
        v[j] = src[j * 64 + lane];
        ss += v[j].x * v[j].x + v[j].y * v[j].y + v[j].z * v[j].z + v[j].w * v[j].w;
    }
    #pragma unroll
    for (int o = 1; o < 64; o <<= 1) ss += __shfl_xor(ss, o);
    const float inv = 1.0f / fmaxf(sqrtf(ss), 1e-12f);

    ushort4* dst = (ushort4*)(z + (size_t)row * ND);
    #pragma unroll
    for (int j = 0; j < 4; ++j) {
        union { __hip_bfloat16 h; unsigned short u; } cu;
        ushort4 pk;
        cu.h = __float2bfloat16(v[j].x * inv); pk.x = cu.u;
        cu.h = __float2bfloat16(v[j].y * inv); pk.y = cu.u;
        cu.h = __float2bfloat16(v[j].z * inv); pk.z = cu.u;
        cu.h = __float2bfloat16(v[j].w * inv); pk.w = cu.u;
        dst[j * 64 + lane] = pk;
    }
    if (lane == 0) {
        const int* lr = labels + row * 4;
        keys[row] = ((lr[3] & 7) << 24) | ((lr[0] & 7) << 16) |
                    ((lr[1] & 7) << 8)  |  (lr[2] & 7);
    }
}

// ---------------------------------------------------------------------------
// simtile: dense 256x256 tiles of S = Z Z^T / TAU.
// R10: NO LDS STAGING. z (8 MB) is L2/L3-resident; MFMA fragments are loaded
// DIRECTLY from global into registers (lane l reads z[rowbase+(l&15)][t*32+
// (l>>4)*8] -- exactly the 16x16x32 operand layout). 4 waves (2x2), each
// computes 128x128 (acc 8x8 f32x4, unified-file ~424 regs, 1 wave/SIMD).
// Per K-32 step: 16 frag loads (reg double-buffer, 1 step ahead) + 64 MFMA.
// Zero barriers / zero LDS in the K-loop; compiler emits fine-grained vmcnt.
// Rationale: 5 schedule variants (R5-R9) all capped at ~8 B/cy/CU on the
// global_load_lds path at 1 block/CU -- the staging pipe, not the schedule,
// was the wall (Common-mistake #7: don't LDS-stage L2-fitting data).
// XCD-local tile mapping (R6) keeps the per-XCD slice ~6 MB (mostly L2-hit).
// ---------------------------------------------------------------------------
__global__ __launch_bounds__(256, 1) void simtile_kernel(
    const unsigned short* __restrict__ z, const int* __restrict__ keys,
    float* __restrict__ partials)
{
    const int B = blockIdx.x;
    const int region = B & 7;            // == XCD under round-robin dispatch
    const int idx    = B >> 3;           // 0..31 within region
    const int ti = (region >> 1) * 4 + (idx >> 3);   // A panel (output rows)
    const int tj = (region & 1) * 8 + (idx & 7);     // B panel (output cols)
    const int R0 = ti * 256, C0 = tj * 256;
    const bool diag = (ti == tj);

    const int tid = threadIdx.x;
    const int lane = tid & 63, w = tid >> 6;          // 4 waves
    const int llo = lane & 15, lhi = lane >> 4;
    const int wm = w >> 1, wn = w & 1;                // 2 x 2 wave grid

    __shared__ float epi[2][256][4];                  // 8 KB
    __shared__ int keyR[256];
    __shared__ int keyC[256];

    if (tid < 256) {
        keyR[tid] = keys[R0 + tid];
        keyC[tid] = keys[C0 + tid];
    }

    // per-lane fragment bases (16B-aligned; row = base + frag*16 + llo)
    const unsigned short* aBase = z + (size_t)(R0 + wm * 128 + llo) * ND + lhi * 8;
    const unsigned short* bBase = z + (size_t)(C0 + wn * 128 + llo) * ND + lhi * 8;

    f32x4 acc[8][8];
    #pragma unroll
    for (int m = 0; m < 8; ++m)
        #pragma unroll
        for (int n = 0; n < 8; ++n)
            acc[m][n] = (f32x4){0.f, 0.f, 0.f, 0.f};

    #define LOADF(A, Bf, T)                                                        \
        do {                                                                       \
            _Pragma("unroll")                                                      \
            for (int m = 0; m < 8; ++m)                                            \
                A[m] = *(const bf16x8*)(aBase + (size_t)(m) * 16 * ND + (T) * 32); \
            _Pragma("unroll")                                                      \
            for (int n = 0; n < 8; ++n)                                            \
                Bf[n] = *(const bf16x8*)(bBase + (size_t)(n) * 16 * ND + (T) * 32);\
        } while (0)

    #define STEP(A, Bf)                                                            \
        do {                                                                       \
            _Pragma("unroll")                                                      \
            for (int m = 0; m < 8; ++m)                                            \
                _Pragma("unroll")                                                  \
                for (int n = 0; n < 8; ++n)                                        \
                    acc[m][n] = __builtin_amdgcn_mfma_f32_16x16x32_bf16(           \
                        A[m], Bf[n], acc[m][n], 0, 0, 0);                          \
        } while (0)

    {
        bf16x8 aC[8], bC[8], aN[8], bN[8];
        LOADF(aC, bC, 0);
        #pragma unroll 1
        for (int t2 = 0; t2 < 16; ++t2) {
            LOADF(aN, bN, 2 * t2 + 1);
            STEP(aC, bC);
            if (t2 < 15) LOADF(aC, bC, 2 * t2 + 2);
            STEP(aN, bN);
        }
    }
    #undef LOADF
    #undef STEP

    __syncthreads();   // keys visible; epi ready for writes

    // -------- epilogue: stats per output row over this block's 256 cols -----
    int kC[8], tcol[8];
    #pragma unroll
    for (int n = 0; n < 8; ++n) {
        tcol[n] = wn * 128 + n * 16 + llo;
        kC[n] = keyC[tcol[n]];
    }

    #pragma unroll
    for (int mp = 0; mp < 8; ++mp) {
        float st[4][4];
        #pragma unroll
        for (int rr = 0; rr < 4; ++rr)
            #pragma unroll
            for (int s = 0; s < 4; ++s) st[rr][s] = 0.0f;

        int kR[4], trow[4];
        #pragma unroll
        for (int rr = 0; rr < 4; ++rr) {
            trow[rr] = wm * 128 + mp * 16 + lhi * 4 + rr;
            kR[rr] = keyR[trow[rr]];
        }
        #pragma unroll
        for (int n = 0; n < 8; ++n) {
            #pragma unroll
            for (int rr = 0; rr < 4; ++rr) {
                const float v = acc[mp][n][rr] * 10.0f;
                const int x = kR[rr] ^ kC[n];
                const float pen = (x & 0xFF000000) ? 1.0f : 0.0f;
                const float g = __expf(v - 10.0f - pen);
                if (!(diag && trow[rr] == tcol[n])) {
                    st[rr][0] += g;
                    if ((x & 0xFFFF0000) == 0) st[rr][1] += v;
                    if ((x & 0xFFFFFF00) == 0) st[rr][2] += v;
                    if (x == 0)                st[rr][3] += v;
                }
            }
        }
        #pragma unroll
        for (int rr = 0; rr < 4; ++rr)
            #pragma unroll
            for (int s = 0; s < 4; ++s) {
                float vv = st[rr][s];
                vv += __shfl_xor(vv, 1);
                vv += __shfl_xor(vv, 2);
                vv += __shfl_xor(vv, 4);
                vv += __shfl_xor(vv, 8);
                st[rr][s] = vv;
            }
        if (llo == 0) {
            #pragma unroll
            for (int rr = 0; rr < 4; ++rr) {
                float4 o; o.x = st[rr][0]; o.y = st[rr][1]; o.z = st[rr][2]; o.w = st[rr][3];
                *(float4*)&epi[wn][trow[rr]][0] = o;
            }
        }
    }
    __syncthreads();

    if (tid < 256) {
        const float4 s0 = *(const float4*)&epi[0][tid][0];
        const float4 s1 = *(const float4*)&epi[1][tid][0];
        float4 o;
        o.x = s0.x + s1.x;
        o.y = s0.y + s1.y;
        o.z = s0.z + s1.z;
        o.w = s0.w + s1.w;
        *(float4*)(partials + ((size_t)tj * NB + R0 + tid) * 4) = o;
    }
}

// ---------------------------------------------------------------------------
// row reduce: block-local LDS histogram of keys (counts), then sum {G,T1,T2,T3}
// over 16 coltiles, per-level per-row values, block-reduce to 6 sums.
// ---------------------------------------------------------------------------
__global__ __launch_bounds__(256) void rowreduce_kernel(
    const float* __restrict__ partials, const int* __restrict__ keys,
    float* __restrict__ blocksums)
{
    const int tid = threadIdx.x;
    const int row = blockIdx.x * 256 + tid;
    const int lane = tid & 63, wid = tid >> 6;

    __shared__ int h3[4096];
    __shared__ int h2[512];
    __shared__ int h1[64];

    for (int i = tid; i < 4096; i += 256) h3[i] = 0;
    __syncthreads();
    for (int i = tid; i < 4096; i += 256) {
        const int k = keys[i];
        const int i3 = (((((k >> 24) & 7) * 8 + ((k >> 16) & 7)) * 8 + ((k >> 8) & 7)) * 8) + (k & 7);
        atomicAdd(&h3[i3], 1);
    }
    __syncthreads();
    for (int i = tid; i < 512; i += 256) {
        int s = 0;
        #pragma unroll
        for (int j = 0; j < 8; ++j) s += h3[i * 8 + j];
        h2[i] = s;
    }
    __syncthreads();
    if (tid < 64) {
        int s = 0;
        #pragma unroll
        for (int j = 0; j < 8; ++j) s += h2[tid * 8 + j];
        h1[tid] = s;
    }
    __syncthreads();

    float G = 0.f, T1 = 0.f, T2 = 0.f, T3 = 0.f;
    for (int ct = 0; ct < 16; ++ct) {
        const float4 u = *(const float4*)(partials + ((size_t)ct * NB + row) * 4);
        G += u.x; T1 += u.y; T2 += u.z; T3 += u.w;
    }
    const float lg = logf(fmaxf(G, 1e-30f)) + 10.0f;   // = logZ + m_i (m_i cancels)

    const int key = keys[row];
    const int i1 = ((key >> 24) & 7) * 8 + ((key >> 16) & 7);
    const int i2 = i1 * 8 + ((key >> 8) & 7);
    const int i3 = i2 * 8 + (key & 7);
    const int C[3] = {h1[i1] - 1, h2[i2] - 1, h3[i3] - 1};
    const float T[3] = {T1, T2, T3};

    float vals[6];
    #pragma unroll
    for (int l = 0; l < 3; ++l) {
        const bool valid = C[l] > 0;
        const float pr = T[l] / fmaxf((float)C[l], 1.0f) - lg;
        vals[2 * l]     = valid ? pr : 0.0f;
        vals[2 * l + 1] = valid ? 1.0f : 0.0f;
    }

    __shared__ float red[4][6];
    #pragma unroll
    for (int s = 0; s < 6; ++s) {
        float v = vals[s];
        #pragma unroll
        for (int o = 32; o > 0; o >>= 1) v += __shfl_xor(v, o);
        vals[s] = v;
    }
    if (lane == 0)
        #pragma unroll
        for (int s = 0; s < 6; ++s) red[wid][s] = vals[s];
    __syncthreads();
    if (tid == 0) {
        #pragma unroll
        for (int s = 0; s < 6; ++s)
            blocksums[blockIdx.x * 8 + s] = red[0][s] + red[1][s] + red[2][s] + red[3][s];
    }
}

// ---------------------------------------------------------------------------
// final: sum 16 block results, run the 3-level scalar loop
// ---------------------------------------------------------------------------
__global__ void final_kernel(const float* __restrict__ blocksums, float* __restrict__ out)
{
    if (threadIdx.x != 0) return;
    float sums[6] = {0, 0, 0, 0, 0, 0};
    for (int b = 0; b < 16; ++b)
        for (int s = 0; s < 6; ++s) sums[s] += blocksums[b * 8 + s];

    const float pen[3] = {2.0f, 1.41421356237309515f, 1.25992104989487319f};
    float total = 0.0f, max_lower = -INFINITY;
    int seen = 0;
    for (int l = 0; l < 3; ++l) {
        const float nv   = sums[2 * l + 1];
        const bool  any  = nv > 0.0f;
        const float mean = sums[2 * l] / fmaxf(nv, 1.0f);
        const float raw  = -mean;                    // TAU/TAU_BASE == 1
        const float lvl  = fmaxf(max_lower, raw);
        if (any) {
            total += lvl * pen[l];
            max_lower = fmaxf(max_lower, lvl);
            seen++;
        }
    }
    out[0] = total / (float)(seen > 0 ? seen : 1);
}

// ---------------------------------------------------------------------------
extern "C" void kernel_launch(void* const* d_in, const int* in_sizes, int n_in,
                              void* d_out, int out_size, void* d_ws, size_t ws_size,
                              hipStream_t stream)
{
    const float* emb    = (const float*)d_in[0];
    const int*   labels = (const int*)d_in[1];
    float*       out    = (float*)d_out;
    char*        ws     = (char*)d_ws;

    // ws layout
    unsigned short* z     = (unsigned short*)(ws);              // 8388608 B
    int*   keys     = (int*)(ws + 8388608);                     // 16384 B
    float* partials = (float*)(ws + 8404992);                   // 1048576 B
    float* bsums    = (float*)(ws + 9453568);                   // 512 B

    prep_kernel<<<NB / 4, 256, 0, stream>>>(emb, labels, z, keys);
    simtile_kernel<<<256, 256, 0, stream>>>(z, keys, partials);
    rowreduce_kernel<<<NB / 256, 256, 0, stream>>>(partials, keys, bsums);
    final_kernel<<<1, 64, 0, stream>>>(bsums, out);
}

// Round 11
// 124.595 us; speedup vs baseline: 1.1948x; 1.1948x over previous
//
#include <hip/hip_runtime.h>
#include <hip/hip_bf16.h>
#include <stdint.h>

#define NB 4096
#define ND 1024

typedef __attribute__((ext_vector_type(8))) short bf16x8;
typedef __attribute__((ext_vector_type(4))) float f32x4;

// ---------------------------------------------------------------------------
// prep: row-normalize to bf16 (wave per row, no block barriers), pack label key
// ---------------------------------------------------------------------------
__global__ __launch_bounds__(256) void prep_kernel(
    const float* __restrict__ emb, const int* __restrict__ labels,
    unsigned short* __restrict__ z, int* __restrict__ keys)
{
    const int wid = threadIdx.x >> 6, lane = threadIdx.x & 63;
    const int row = blockIdx.x * 4 + wid;
    const float4* src = (const float4*)(emb + (size_t)row * ND);
    float4 v[4];
    float ss = 0.0f;
    #pragma unroll
    for (int j = 0; j < 4; ++j) {
        v[j] = src[j * 64 + lane];
        ss += v[j].x * v[j].x + v[j].y * v[j].y + v[j].z * v[j].z + v[j].w * v[j].w;
    }
    #pragma unroll
    for (int o = 1; o < 64; o <<= 1) ss += __shfl_xor(ss, o);
    const float inv = 1.0f / fmaxf(sqrtf(ss), 1e-12f);

    ushort4* dst = (ushort4*)(z + (size_t)row * ND);
    #pragma unroll
    for (int j = 0; j < 4; ++j) {
        union { __hip_bfloat16 h; unsigned short u; } cu;
        ushort4 pk;
        cu.h = __float2bfloat16(v[j].x * inv); pk.x = cu.u;
        cu.h = __float2bfloat16(v[j].y * inv); pk.y = cu.u;
        cu.h = __float2bfloat16(v[j].z * inv); pk.z = cu.u;
        cu.h = __float2bfloat16(v[j].w * inv); pk.w = cu.u;
        dst[j * 64 + lane] = pk;
    }
    if (lane == 0) {
        const int* lr = labels + row * 4;
        keys[row] = ((lr[3] & 7) << 24) | ((lr[0] & 7) << 16) |
                    ((lr[1] & 7) << 8)  |  (lr[2] & 7);
    }
}

// ---------------------------------------------------------------------------
// simtile: dense 256x256 tiles of S = Z Z^T / TAU.
// R11: R10's zero-LDS direct-from-global K-loop, REGISTER-SIZED. R10 spilled
// (acc 8x8 = 256 regs + frags > 256-cap -> WRITE_SIZE 274 MB of scratch).
// Now: 8 waves (2Mx4N), per-wave 128x64 -> acc 8x4 f32x4 (128) + dbuf frags
// A8+B4 (96) + addr ~ 240 VGPR < 256 cap at launch_bounds(512,2).
// Lane l loads z[rowbase+(l&15)][t*32+(l>>4)*8] = exact 16x16x32 frag layout.
// Per K-32 step/CU: 96 KB loads, 32 KB unique (fits L1; redundancy L1-hit).
// No barriers in K-loop; 2 waves/SIMD overlap loads with MFMA (m114).
// XCD-local tile mapping (R6) keeps per-XCD slice mostly L2-resident.
// ---------------------------------------------------------------------------
__global__ __launch_bounds__(512, 2) void simtile_kernel(
    const unsigned short* __restrict__ z, const int* __restrict__ keys,
    float* __restrict__ partials)
{
    const int B = blockIdx.x;
    const int region = B & 7;            // == XCD under round-robin dispatch
    const int idx    = B >> 3;           // 0..31 within region
    const int ti = (region >> 1) * 4 + (idx >> 3);   // A panel (output rows)
    const int tj = (region & 1) * 8 + (idx & 7);     // B panel (output cols)
    const int R0 = ti * 256, C0 = tj * 256;
    const bool diag = (ti == tj);

    const int tid = threadIdx.x;
    const int lane = tid & 63, w = tid >> 6;          // 8 waves
    const int llo = lane & 15, lhi = lane >> 4;
    const int wm = w >> 2, wn = w & 3;                // 2 x 4 wave grid

    __shared__ float epi[4][256][4];                  // 16 KB
    __shared__ int keyR[256];
    __shared__ int keyC[256];

    if (tid < 256) {
        keyR[tid] = keys[R0 + tid];
        keyC[tid] = keys[C0 + tid];
    }

    // per-lane fragment bases (16B-aligned; frag row = base + frag*16 + llo)
    const unsigned short* aBase = z + (size_t)(R0 + wm * 128 + llo) * ND + lhi * 8;
    const unsigned short* bBase = z + (size_t)(C0 + wn * 64 + llo) * ND + lhi * 8;

    f32x4 acc[8][4];
    #pragma unroll
    for (int m = 0; m < 8; ++m)
        #pragma unroll
        for (int n = 0; n < 4; ++n)
            acc[m][n] = (f32x4){0.f, 0.f, 0.f, 0.f};

    #define LOADF(A, Bf, T)                                                        \
        do {                                                                       \
            _Pragma("unroll")                                                      \
            for (int m = 0; m < 8; ++m)                                            \
                A[m] = *(const bf16x8*)(aBase + (size_t)(m) * 16 * ND + (T) * 32); \
            _Pragma("unroll")                                                      \
            for (int n = 0; n < 4; ++n)                                            \
                Bf[n] = *(const bf16x8*)(bBase + (size_t)(n) * 16 * ND + (T) * 32);\
        } while (0)

    #define STEP(A, Bf)                                                            \
        do {                                                                       \
            _Pragma("unroll")                                                      \
            for (int m = 0; m < 8; ++m)                                            \
                _Pragma("unroll")                                                  \
                for (int n = 0; n < 4; ++n)                                        \
                    acc[m][n] = __builtin_amdgcn_mfma_f32_16x16x32_bf16(           \
                        A[m], Bf[n], acc[m][n], 0, 0, 0);                          \
        } while (0)

    {
        bf16x8 aC[8], bC[4], aN[8], bN[4];
        LOADF(aC, bC, 0);
        #pragma unroll 1
        for (int t2 = 0; t2 < 16; ++t2) {
            LOADF(aN, bN, 2 * t2 + 1);
            STEP(aC, bC);
            if (t2 < 15) LOADF(aC, bC, 2 * t2 + 2);
            STEP(aN, bN);
        }
    }
    #undef LOADF
    #undef STEP

    __syncthreads();   // keys visible; epi ready for writes

    // -------- epilogue: stats per output row over this block's 256 cols -----
    int kC[4], tcol[4];
    #pragma unroll
    for (int n = 0; n < 4; ++n) {
        tcol[n] = wn * 64 + n * 16 + llo;
        kC[n] = keyC[tcol[n]];
    }

    #pragma unroll
    for (int mp = 0; mp < 8; ++mp) {
        float st[4][4];
        #pragma unroll
        for (int rr = 0; rr < 4; ++rr)
            #pragma unroll
            for (int s = 0; s < 4; ++s) st[rr][s] = 0.0f;

        int kR[4], trow[4];
        #pragma unroll
        for (int rr = 0; rr < 4; ++rr) {
            trow[rr] = wm * 128 + mp * 16 + lhi * 4 + rr;
            kR[rr] = keyR[trow[rr]];
        }
        #pragma unroll
        for (int n = 0; n < 4; ++n) {
            #pragma unroll
            for (int rr = 0; rr < 4; ++rr) {
                const float v = acc[mp][n][rr] * 10.0f;
                const int x = kR[rr] ^ kC[n];
                const float pen = (x & 0xFF000000) ? 1.0f : 0.0f;
                const float g = __expf(v - 10.0f - pen);
                if (!(diag && trow[rr] == tcol[n])) {
                    st[rr][0] += g;
                    if ((x & 0xFFFF0000) == 0) st[rr][1] += v;
                    if ((x & 0xFFFFFF00) == 0) st[rr][2] += v;
                    if (x == 0)                st[rr][3] += v;
                }
            }
        }
        #pragma unroll
        for (int rr = 0; rr < 4; ++rr)
            #pragma unroll
            for (int s = 0; s < 4; ++s) {
                float vv = st[rr][s];
                vv += __shfl_xor(vv, 1);
                vv += __shfl_xor(vv, 2);
                vv += __shfl_xor(vv, 4);
                vv += __shfl_xor(vv, 8);
                st[rr][s] = vv;
            }
        if (llo == 0) {
            #pragma unroll
            for (int rr = 0; rr < 4; ++rr) {
                float4 o; o.x = st[rr][0]; o.y = st[rr][1]; o.z = st[rr][2]; o.w = st[rr][3];
                *(float4*)&epi[wn][trow[rr]][0] = o;
            }
        }
    }
    __syncthreads();

    if (tid < 256) {
        const float4 s0 = *(const float4*)&epi[0][tid][0];
        const float4 s1 = *(const float4*)&epi[1][tid][0];
        const float4 s2 = *(const float4*)&epi[2][tid][0];
        const float4 s3 = *(const float4*)&epi[3][tid][0];
        float4 o;
        o.x = s0.x + s1.x + s2.x + s3.x;
        o.y = s0.y + s1.y + s2.y + s3.y;
        o.z = s0.z + s1.z + s2.z + s3.z;
        o.w = s0.w + s1.w + s2.w + s3.w;
        *(float4*)(partials + ((size_t)tj * NB + R0 + tid) * 4) = o;
    }
}

// ---------------------------------------------------------------------------
// row reduce: block-local LDS histogram of keys (counts), then sum {G,T1,T2,T3}
// over 16 coltiles, per-level per-row values, block-reduce to 6 sums.
// ---------------------------------------------------------------------------
__global__ __launch_bounds__(256) void rowreduce_kernel(
    const float* __restrict__ partials, const int* __restrict__ keys,
    float* __restrict__ blocksums)
{
    const int tid = threadIdx.x;
    const int row = blockIdx.x * 256 + tid;
    const int lane = tid & 63, wid = tid >> 6;

    __shared__ int h3[4096];
    __shared__ int h2[512];
    __shared__ int h1[64];

    for (int i = tid; i < 4096; i += 256) h3[i] = 0;
    __syncthreads();
    for (int i = tid; i < 4096; i += 256) {
        const int k = keys[i];
        const int i3 = (((((k >> 24) & 7) * 8 + ((k >> 16) & 7)) * 8 + ((k >> 8) & 7)) * 8) + (k & 7);
        atomicAdd(&h3[i3], 1);
    }
    __syncthreads();
    for (int i = tid; i < 512; i += 256) {
        int s = 0;
        #pragma unroll
        for (int j = 0; j < 8; ++j) s += h3[i * 8 + j];
        h2[i] = s;
    }
    __syncthreads();
    if (tid < 64) {
        int s = 0;
        #pragma unroll
        for (int j = 0; j < 8; ++j) s += h2[tid * 8 + j];
        h1[tid] = s;
    }
    __syncthreads();

    float G = 0.f, T1 = 0.f, T2 = 0.f, T3 = 0.f;
    for (int ct = 0; ct < 16; ++ct) {
        const float4 u = *(const float4*)(partials + ((size_t)ct * NB + row) * 4);
        G += u.x; T1 += u.y; T2 += u.z; T3 += u.w;
    }
    const float lg = logf(fmaxf(G, 1e-30f)) + 10.0f;   // = logZ + m_i (m_i cancels)

    const int key = keys[row];
    const int i1 = ((key >> 24) & 7) * 8 + ((key >> 16) & 7);
    const int i2 = i1 * 8 + ((key >> 8) & 7);
    const int i3 = i2 * 8 + (key & 7);
    const int C[3] = {h1[i1] - 1, h2[i2] - 1, h3[i3] - 1};
    const float T[3] = {T1, T2, T3};

    float vals[6];
    #pragma unroll
    for (int l = 0; l < 3; ++l) {
        const bool valid = C[l] > 0;
        const float pr = T[l] / fmaxf((float)C[l], 1.0f) - lg;
        vals[2 * l]     = valid ? pr : 0.0f;
        vals[2 * l + 1] = valid ? 1.0f : 0.0f;
    }

    __shared__ float red[4][6];
    #pragma unroll
    for (int s = 0; s < 6; ++s) {
        float v = vals[s];
        #pragma unroll
        for (int o = 32; o > 0; o >>= 1) v += __shfl_xor(v, o);
        vals[s] = v;
    }
    if (lane == 0)
        #pragma unroll
        for (int s = 0; s < 6; ++s) red[wid][s] = vals[s];
    __syncthreads();
    if (tid == 0) {
        #pragma unroll
        for (int s = 0; s < 6; ++s)
            blocksums[blockIdx.x * 8 + s] = red[0][s] + red[1][s] + red[2][s] + red[3][s];
    }
}

// ---------------------------------------------------------------------------
// final: sum 16 block results, run the 3-level scalar loop
// ---------------------------------------------------------------------------
__global__ void final_kernel(const float* __restrict__ blocksums, float* __restrict__ out)
{
    if (threadIdx.x != 0) return;
    float sums[6] = {0, 0, 0, 0, 0, 0};
    for (int b = 0; b < 16; ++b)
        for (int s = 0; s < 6; ++s) sums[s] += blocksums[b * 8 + s];

    const float pen[3] = {2.0f, 1.41421356237309515f, 1.25992104989487319f};
    float total = 0.0f, max_lower = -INFINITY;
    int seen = 0;
    for (int l = 0; l < 3; ++l) {
        const float nv   = sums[2 * l + 1];
        const bool  any  = nv > 0.0f;
        const float mean = sums[2 * l] / fmaxf(nv, 1.0f);
        const float raw  = -mean;                    // TAU/TAU_BASE == 1
        const float lvl  = fmaxf(max_lower, raw);
        if (any) {
            total += lvl * pen[l];
            max_lower = fmaxf(max_lower, lvl);
            seen++;
        }
    }
    out[0] = total / (float)(seen > 0 ? seen : 1);
}

// ---------------------------------------------------------------------------
extern "C" void kernel_launch(void* const* d_in, const int* in_sizes, int n_in,
                              void* d_out, int out_size, void* d_ws, size_t ws_size,
                              hipStream_t stream)
{
    const float* emb    = (const float*)d_in[0];
    const int*   labels = (const int*)d_in[1];
    float*       out    = (float*)d_out;
    char*        ws     = (char*)d_ws;

    // ws layout
    unsigned short* z     = (unsigned short*)(ws);              // 8388608 B
    int*   keys     = (int*)(ws + 8388608);                     // 16384 B
    float* partials = (float*)(ws + 8404992);                   // 1048576 B
    float* bsums    = (float*)(ws + 9453568);                   // 512 B

    prep_kernel<<<NB / 4, 256, 0, stream>>>(emb, labels, z, keys);
    simtile_kernel<<<256, 512, 0, stream>>>(z, keys, partials);
    rowreduce_kernel<<<NB / 256, 256, 0, stream>>>(partials, keys, bsums);
    final_kernel<<<1, 64, 0, stream>>>(bsums, out);
}

// Round 12
// 71.035 us; speedup vs baseline: 2.0957x; 1.7540x over previous
//
#include <hip/hip_runtime.h>
#include <hip/hip_bf16.h>
#include <stdint.h>

#define NB 4096
#define ND 1024

typedef __attribute__((ext_vector_type(8))) short bf16x8;
typedef __attribute__((ext_vector_type(4))) float f32x4;

// ---------------------------------------------------------------------------
// prep: row-normalize to bf16 and write FRAGMENT-ORDERED zf, pack label key.
// zf layout: frag (rowtile rt = row/16, ktile t = k/32) is a contiguous 1KB
// block; within it, lane L = (row%16) + 16*((k%32)/8) holds 8 bf16 (16B).
// This is exactly the mfma_f32_16x16x32_bf16 A/B per-lane operand layout, so
// simtile loads fragments as fully-coalesced global_load_dwordx4.
// Producer: lane l holds k in [16l, 16l+16) -> its two 8-chunks live in frag
// (row>>4, l>>1) at lanes (row&15)+16*c, c = (l&1)*2 and c+1.
// ---------------------------------------------------------------------------
__global__ __launch_bounds__(256) void prep_kernel(
    const float* __restrict__ emb, const int* __restrict__ labels,
    unsigned short* __restrict__ zf, int* __restrict__ keys)
{
    const int wid = threadIdx.x >> 6, lane = threadIdx.x & 63;
    const int row = blockIdx.x * 4 + wid;
    const float4* src = (const float4*)(emb + (size_t)row * ND) + lane * 4;
    float4 v[4];
    float ss = 0.0f;
    #pragma unroll
    for (int j = 0; j < 4; ++j) {
        v[j] = src[j];
        ss += v[j].x * v[j].x + v[j].y * v[j].y + v[j].z * v[j].z + v[j].w * v[j].w;
    }
    #pragma unroll
    for (int o = 1; o < 64; o <<= 1) ss += __shfl_xor(ss, o);
    const float inv = 1.0f / fmaxf(sqrtf(ss), 1e-12f);

    union { __hip_bfloat16 h; unsigned short u; } cu;
    ushort4 lo, hi;
    cu.h = __float2bfloat16(v[0].x * inv); lo.x = cu.u;
    cu.h = __float2bfloat16(v[0].y * inv); lo.y = cu.u;
    cu.h = __float2bfloat16(v[0].z * inv); lo.z = cu.u;
    cu.h = __float2bfloat16(v[0].w * inv); lo.w = cu.u;
    cu.h = __float2bfloat16(v[1].x * inv); hi.x = cu.u;   // reuse hi as tmp
    lo = lo;  // (keep order explicit below)
    ushort4 c0v, c1v;
    c0v.x = lo.x; c0v.y = lo.y; c0v.z = lo.z; c0v.w = lo.w;
    cu.h = __float2bfloat16(v[1].x * inv); // k+4
    unsigned short k4 = cu.u;
    cu.h = __float2bfloat16(v[1].y * inv); unsigned short k5 = cu.u;
    cu.h = __float2bfloat16(v[1].z * inv); unsigned short k6 = cu.u;
    cu.h = __float2bfloat16(v[1].w * inv); unsigned short k7 = cu.u;
    cu.h = __float2bfloat16(v[2].x * inv); unsigned short k8 = cu.u;
    cu.h = __float2bfloat16(v[2].y * inv); unsigned short k9 = cu.u;
    cu.h = __float2bfloat16(v[2].z * inv); unsigned short kA = cu.u;
    cu.h = __float2bfloat16(v[2].w * inv); unsigned short kB = cu.u;
    cu.h = __float2bfloat16(v[3].x * inv); unsigned short kC = cu.u;
    cu.h = __float2bfloat16(v[3].y * inv); unsigned short kD = cu.u;
    cu.h = __float2bfloat16(v[3].z * inv); unsigned short kE = cu.u;
    cu.h = __float2bfloat16(v[3].w * inv); unsigned short kF = cu.u;

    const size_t frag = (size_t)(row >> 4) * 32 + (lane >> 1);
    const int    L0   = (row & 15) + 16 * ((lane & 1) * 2);
    unsigned short* d = zf + frag * 512 + (size_t)L0 * 8;
    ushort4 w0; w0.x = c0v.x; w0.y = c0v.y; w0.z = c0v.z; w0.w = c0v.w;
    ushort4 w1; w1.x = k4; w1.y = k5; w1.z = k6; w1.w = k7;
    ushort4 w2; w2.x = k8; w2.y = k9; w2.z = kA; w2.w = kB;
    ushort4 w3; w3.x = kC; w3.y = kD; w3.z = kE; w3.w = kF;
    *(ushort4*)(d)       = w0;   // k+0..3
    *(ushort4*)(d + 4)   = w1;   // k+4..7   (same 16B? no: d is ushort*, +4 = 8B)
    *(ushort4*)(d + 128) = w2;   // next c (16 lanes * 8) : k+8..11
    *(ushort4*)(d + 132) = w3;   // k+12..15

    if (lane == 0) {
        const int* lr = labels + row * 4;
        keys[row] = ((lr[3] & 7) << 24) | ((lr[0] & 7) << 16) |
                    ((lr[1] & 7) << 8)  |  (lr[2] & 7);
    }
}

// ---------------------------------------------------------------------------
// simtile: dense 256x256 tiles of S = Z Z^T / TAU.
// R12: zero-LDS direct-from-global K-loop (R11 structure) over FRAGMENT-
// ORDERED zf. Each frag load = global_load_dwordx4 with lane-consecutive
// addresses (1KB contiguous) -- coalesced, sequential lines, no L1 set
// aliasing (R11's 2KB-stride gather aliased ~2 L1 sets -> all-miss).
// 8 waves (2Mx4N), 128x64/wave: acc 8x4 f32x4 (AGPR) + dbuf frags ~96 VGPR.
// No barriers in K-loop; 2 waves/SIMD overlap; XCD-local mapping (R6).
// ---------------------------------------------------------------------------
__global__ __launch_bounds__(512, 2) void simtile_kernel(
    const unsigned short* __restrict__ zf, const int* __restrict__ keys,
    float* __restrict__ partials)
{
    const int B = blockIdx.x;
    const int region = B & 7;            // == XCD under round-robin dispatch
    const int idx    = B >> 3;           // 0..31 within region
    const int ti = (region >> 1) * 4 + (idx >> 3);   // A panel (output rows)
    const int tj = (region & 1) * 8 + (idx & 7);     // B panel (output cols)
    const int R0 = ti * 256, C0 = tj * 256;
    const bool diag = (ti == tj);

    const int tid = threadIdx.x;
    const int lane = tid & 63, w = tid >> 6;          // 8 waves
    const int llo = lane & 15, lhi = lane >> 4;
    const int wm = w >> 2, wn = w & 3;                // 2 x 4 wave grid

    __shared__ float epi[4][256][4];                  // 16 KB
    __shared__ int keyR[256];
    __shared__ int keyC[256];

    if (tid < 256) {
        keyR[tid] = keys[R0 + tid];
        keyC[tid] = keys[C0 + tid];
    }

    // fragment bases: rowtile rt covers rows rt*16..+16; frag(rt,t) is 1KB.
    const unsigned short* aF = zf + ((size_t)(ti * 16 + wm * 8) * 32) * 512 + lane * 8;
    const unsigned short* bF = zf + ((size_t)(tj * 16 + wn * 4) * 32) * 512 + lane * 8;

    f32x4 acc[8][4];
    #pragma unroll
    for (int m = 0; m < 8; ++m)
        #pragma unroll
        for (int n = 0; n < 4; ++n)
            acc[m][n] = (f32x4){0.f, 0.f, 0.f, 0.f};

    #define LOADF(A, Bf, T)                                                        \
        do {                                                                       \
            _Pragma("unroll")                                                      \
            for (int m = 0; m < 8; ++m)                                            \
                A[m] = *(const bf16x8*)(aF + ((size_t)(m) * 32 + (T)) * 512);      \
            _Pragma("unroll")                                                      \
            for (int n = 0; n < 4; ++n)                                            \
                Bf[n] = *(const bf16x8*)(bF + ((size_t)(n) * 32 + (T)) * 512);     \
        } while (0)

    #define STEP(A, Bf)                                                            \
        do {                                                                       \
            _Pragma("unroll")                                                      \
            for (int m = 0; m < 8; ++m)                                            \
                _Pragma("unroll")                                                  \
                for (int n = 0; n < 4; ++n)                                        \
                    acc[m][n] = __builtin_amdgcn_mfma_f32_16x16x32_bf16(           \
                        A[m], Bf[n], acc[m][n], 0, 0, 0);                          \
        } while (0)

    {
        bf16x8 aC[8], bC[4], aN[8], bN[4];
        LOADF(aC, bC, 0);
        #pragma unroll 1
        for (int t2 = 0; t2 < 16; ++t2) {
            LOADF(aN, bN, 2 * t2 + 1);
            STEP(aC, bC);
            if (t2 < 15) LOADF(aC, bC, 2 * t2 + 2);
            STEP(aN, bN);
        }
    }
    #undef LOADF
    #undef STEP

    __syncthreads();   // keys visible; epi ready for writes

    // -------- epilogue: stats per output row over this block's 256 cols -----
    int kC[4], tcol[4];
    #pragma unroll
    for (int n = 0; n < 4; ++n) {
        tcol[n] = wn * 64 + n * 16 + llo;
        kC[n] = keyC[tcol[n]];
    }

    #pragma unroll
    for (int mp = 0; mp < 8; ++mp) {
        float st[4][4];
        #pragma unroll
        for (int rr = 0; rr < 4; ++rr)
            #pragma unroll
            for (int s = 0; s < 4; ++s) st[rr][s] = 0.0f;

        int kR[4], trow[4];
        #pragma unroll
        for (int rr = 0; rr < 4; ++rr) {
            trow[rr] = wm * 128 + mp * 16 + lhi * 4 + rr;
            kR[rr] = keyR[trow[rr]];
        }
        #pragma unroll
        for (int n = 0; n < 4; ++n) {
            #pragma unroll
            for (int rr = 0; rr < 4; ++rr) {
                const float v = acc[mp][n][rr] * 10.0f;
                const int x = kR[rr] ^ kC[n];
                const float pen = (x & 0xFF000000) ? 1.0f : 0.0f;
                const float g = __expf(v - 10.0f - pen);
                if (!(diag && trow[rr] == tcol[n])) {
                    st[rr][0] += g;
                    if ((x & 0xFFFF0000) == 0) st[rr][1] += v;
                    if ((x & 0xFFFFFF00) == 0) st[rr][2] += v;
                    if (x == 0)                st[rr][3] += v;
                }
            }
        }
        #pragma unroll
        for (int rr = 0; rr < 4; ++rr)
            #pragma unroll
            for (int s = 0; s < 4; ++s) {
                float vv = st[rr][s];
                vv += __shfl_xor(vv, 1);
                vv += __shfl_xor(vv, 2);
                vv += __shfl_xor(vv, 4);
                vv += __shfl_xor(vv, 8);
                st[rr][s] = vv;
            }
        if (llo == 0) {
            #pragma unroll
            for (int rr = 0; rr < 4; ++rr) {
                float4 o; o.x = st[rr][0]; o.y = st[rr][1]; o.z = st[rr][2]; o.w = st[rr][3];
                *(float4*)&epi[wn][trow[rr]][0] = o;
            }
        }
    }
    __syncthreads();

    if (tid < 256) {
        const float4 s0 = *(const float4*)&epi[0][tid][0];
        const float4 s1 = *(const float4*)&epi[1][tid][0];
        const float4 s2 = *(const float4*)&epi[2][tid][0];
        const float4 s3 = *(const float4*)&epi[3][tid][0];
        float4 o;
        o.x = s0.x + s1.x + s2.x + s3.x;
        o.y = s0.y + s1.y + s2.y + s3.y;
        o.z = s0.z + s1.z + s2.z + s3.z;
        o.w = s0.w + s1.w + s2.w + s3.w;
        *(float4*)(partials + ((size_t)tj * NB + R0 + tid) * 4) = o;
    }
}

// ---------------------------------------------------------------------------
// row reduce: block-local LDS histogram of keys (counts), then sum {G,T1,T2,T3}
// over 16 coltiles, per-level per-row values, block-reduce to 6 sums.
// ---------------------------------------------------------------------------
__global__ __launch_bounds__(256) void rowreduce_kernel(
    const float* __restrict__ partials, const int* __restrict__ keys,
    float* __restrict__ blocksums)
{
    const int tid = threadIdx.x;
    const int row = blockIdx.x * 256 + tid;
    const int lane = tid & 63, wid = tid >> 6;

    __shared__ int h3[4096];
    __shared__ int h2[512];
    __shared__ int h1[64];

    for (int i = tid; i < 4096; i += 256) h3[i] = 0;
    __syncthreads();
    for (int i = tid; i < 4096; i += 256) {
        const int k = keys[i];
        const int i3 = (((((k >> 24) & 7) * 8 + ((k >> 16) & 7)) * 8 + ((k >> 8) & 7)) * 8) + (k & 7);
        atomicAdd(&h3[i3], 1);
    }
    __syncthreads();
    for (int i = tid; i < 512; i += 256) {
        int s = 0;
        #pragma unroll
        for (int j = 0; j < 8; ++j) s += h3[i * 8 + j];
        h2[i] = s;
    }
    __syncthreads();
    if (tid < 64) {
        int s = 0;
        #pragma unroll
        for (int j = 0; j < 8; ++j) s += h2[tid * 8 + j];
        h1[tid] = s;
    }
    __syncthreads();

    float G = 0.f, T1 = 0.f, T2 = 0.f, T3 = 0.f;
    for (int ct = 0; ct < 16; ++ct) {
        const float4 u = *(const float4*)(partials + ((size_t)ct * NB + row) * 4);
        G += u.x; T1 += u.y; T2 += u.z; T3 += u.w;
    }
    const float lg = logf(fmaxf(G, 1e-30f)) + 10.0f;   // = logZ + m_i (m_i cancels)

    const int key = keys[row];
    const int i1 = ((key >> 24) & 7) * 8 + ((key >> 16) & 7);
    const int i2 = i1 * 8 + ((key >> 8) & 7);
    const int i3 = i2 * 8 + (key & 7);
    const int C[3] = {h1[i1] - 1, h2[i2] - 1, h3[i3] - 1};
    const float T[3] = {T1, T2, T3};

    float vals[6];
    #pragma unroll
    for (int l = 0; l < 3; ++l) {
        const bool valid = C[l] > 0;
        const float pr = T[l] / fmaxf((float)C[l], 1.0f) - lg;
        vals[2 * l]     = valid ? pr : 0.0f;
        vals[2 * l + 1] = valid ? 1.0f : 0.0f;
    }

    __shared__ float red[4][6];
    #pragma unroll
    for (int s = 0; s < 6; ++s) {
        float v = vals[s];
        #pragma unroll
        for (int o = 32; o > 0; o >>= 1) v += __shfl_xor(v, o);
        vals[s] = v;
    }
    if (lane == 0)
        #pragma unroll
        for (int s = 0; s < 6; ++s) red[wid][s] = vals[s];
    __syncthreads();
    if (tid == 0) {
        #pragma unroll
        for (int s = 0; s < 6; ++s)
            blocksums[blockIdx.x * 8 + s] = red[0][s] + red[1][s] + red[2][s] + red[3][s];
    }
}

// ---------------------------------------------------------------------------
// final: sum 16 block results, run the 3-level scalar loop
// ---------------------------------------------------------------------------
__global__ void final_kernel(const float* __restrict__ blocksums, float* __restrict__ out)
{
    if (threadIdx.x != 0) return;
    float sums[6] = {0, 0, 0, 0, 0, 0};
    for (int b = 0; b < 16; ++b)
        for (int s = 0; s < 6; ++s) sums[s] += blocksums[b * 8 + s];

    const float pen[3] = {2.0f, 1.41421356237309515f, 1.25992104989487319f};
    float total = 0.0f, max_lower = -INFINITY;
    int seen = 0;
    for (int l = 0; l < 3; ++l) {
        const float nv   = sums[2 * l + 1];
        const bool  any  = nv > 0.0f;
        const float mean = sums[2 * l] / fmaxf(nv, 1.0f);
        const float raw  = -mean;                    // TAU/TAU_BASE == 1
        const float lvl  = fmaxf(max_lower, raw);
        if (any) {
            total += lvl * pen[l];
            max_lower = fmaxf(max_lower, lvl);
            seen++;
        }
    }
    out[0] = total / (float)(seen > 0 ? seen : 1);
}

// ---------------------------------------------------------------------------
extern "C" void kernel_launch(void* const* d_in, const int* in_sizes, int n_in,
                              void* d_out, int out_size, void* d_ws, size_t ws_size,
                              hipStream_t stream)
{
    const float* emb    = (const float*)d_in[0];
    const int*   labels = (const int*)d_in[1];
    float*       out    = (float*)d_out;
    char*        ws     = (char*)d_ws;

    // ws layout
    unsigned short* zf    = (unsigned short*)(ws);              // 8388608 B (frag-ordered)
    int*   keys     = (int*)(ws + 8388608);                     // 16384 B
    float* partials = (float*)(ws + 8404992);                   // 1048576 B
    float* bsums    = (float*)(ws + 9453568);                   // 512 B

    prep_kernel<<<NB / 4, 256, 0, stream>>>(emb, labels, zf, keys);
    simtile_kernel<<<256, 512, 0, stream>>>(zf, keys, partials);
    rowreduce_kernel<<<NB / 256, 256, 0, stream>>>(partials, keys, bsums);
    final_kernel<<<1, 64, 0, stream>>>(bsums, out);
}

// Round 13
// 61.090 us; speedup vs baseline: 2.4369x; 1.1628x over previous
//
#include <hip/hip_runtime.h>
#include <hip/hip_bf16.h>
#include <stdint.h>

#define NB 4096
#define ND 1024

typedef __attribute__((ext_vector_type(8))) short bf16x8;
typedef __attribute__((ext_vector_type(4))) float f32x4;

// ---------------------------------------------------------------------------
// prep: row-normalize to bf16 and write FRAGMENT-ORDERED zf, pack label key.
// zf layout: frag (rowtile rt = row/16, ktile t = k/32) is a contiguous 1KB
// block; within it, lane L = (row%16) + 16*((k%32)/8) holds 8 bf16 (16B).
// (byte-identical to R12's prep -- passed.)
// ---------------------------------------------------------------------------
__global__ __launch_bounds__(256) void prep_kernel(
    const float* __restrict__ emb, const int* __restrict__ labels,
    unsigned short* __restrict__ zf, int* __restrict__ keys)
{
    const int wid = threadIdx.x >> 6, lane = threadIdx.x & 63;
    const int row = blockIdx.x * 4 + wid;
    const float4* src = (const float4*)(emb + (size_t)row * ND) + lane * 4;
    float4 v[4];
    float ss = 0.0f;
    #pragma unroll
    for (int j = 0; j < 4; ++j) {
        v[j] = src[j];
        ss += v[j].x * v[j].x + v[j].y * v[j].y + v[j].z * v[j].z + v[j].w * v[j].w;
    }
    #pragma unroll
    for (int o = 1; o < 64; o <<= 1) ss += __shfl_xor(ss, o);
    const float inv = 1.0f / fmaxf(sqrtf(ss), 1e-12f);

    union { __hip_bfloat16 h; unsigned short u; } cu;
    unsigned short kv[16];
    cu.h = __float2bfloat16(v[0].x * inv); kv[0] = cu.u;
    cu.h = __float2bfloat16(v[0].y * inv); kv[1] = cu.u;
    cu.h = __float2bfloat16(v[0].z * inv); kv[2] = cu.u;
    cu.h = __float2bfloat16(v[0].w * inv); kv[3] = cu.u;
    cu.h = __float2bfloat16(v[1].x * inv); kv[4] = cu.u;
    cu.h = __float2bfloat16(v[1].y * inv); kv[5] = cu.u;
    cu.h = __float2bfloat16(v[1].z * inv); kv[6] = cu.u;
    cu.h = __float2bfloat16(v[1].w * inv); kv[7] = cu.u;
    cu.h = __float2bfloat16(v[2].x * inv); kv[8] = cu.u;
    cu.h = __float2bfloat16(v[2].y * inv); kv[9] = cu.u;
    cu.h = __float2bfloat16(v[2].z * inv); kv[10] = cu.u;
    cu.h = __float2bfloat16(v[2].w * inv); kv[11] = cu.u;
    cu.h = __float2bfloat16(v[3].x * inv); kv[12] = cu.u;
    cu.h = __float2bfloat16(v[3].y * inv); kv[13] = cu.u;
    cu.h = __float2bfloat16(v[3].z * inv); kv[14] = cu.u;
    cu.h = __float2bfloat16(v[3].w * inv); kv[15] = cu.u;

    const size_t frag = (size_t)(row >> 4) * 32 + (lane >> 1);
    const int    L0   = (row & 15) + 16 * ((lane & 1) * 2);
    unsigned short* d = zf + frag * 512 + (size_t)L0 * 8;
    ushort4 w0; w0.x = kv[0];  w0.y = kv[1];  w0.z = kv[2];  w0.w = kv[3];
    ushort4 w1; w1.x = kv[4];  w1.y = kv[5];  w1.z = kv[6];  w1.w = kv[7];
    ushort4 w2; w2.x = kv[8];  w2.y = kv[9];  w2.z = kv[10]; w2.w = kv[11];
    ushort4 w3; w3.x = kv[12]; w3.y = kv[13]; w3.z = kv[14]; w3.w = kv[15];
    *(ushort4*)(d)       = w0;
    *(ushort4*)(d + 4)   = w1;
    *(ushort4*)(d + 128) = w2;
    *(ushort4*)(d + 132) = w3;

    if (lane == 0) {
        const int* lr = labels + row * 4;
        keys[row] = ((lr[3] & 7) << 24) | ((lr[0] & 7) << 16) |
                    ((lr[1] & 7) << 8)  |  (lr[2] & 7);
    }
}

// ---------------------------------------------------------------------------
// simtile: upper-triangle 128x128 tiles of S = Z Z^T / TAU, direct frag loads.
// R13: triangle (x0.5 FLOPs; true MFMA floor 7.2 us -- 19.4 cy/MFMA per SIMD,
// not 4.85: that's per-CU). 528 blocks of 4 waves (2x2 of 64x64); ~2 blocks/CU
// => 2 waves/SIMD from INDEPENDENT blocks (m114 implicit overlap, no barrier
// coupling). Direct global frag loads from frag-ordered zf (R12: coalesced,
// 0 conflicts, no DMA-pipe wall). acc 4x4 f32x4 = 64 regs; ~180 VGPR, no
// spill at launch_bounds(256,2). Dual-sided epilogue (R2-proven): side A ->
// I-rows (shfl over llo), side B -> J-rows (shfl over lhi); every
// partials[ct][row] written exactly once. XCD chunking: 528 = 8*66 exact.
// ---------------------------------------------------------------------------
__global__ __launch_bounds__(256, 2) void simtile_kernel(
    const unsigned short* __restrict__ zf, const int* __restrict__ keys,
    float* __restrict__ partials)
{
    const int b = blockIdx.x;
    const int p = (b & 7) * 66 + (b >> 3);   // XCD-contiguous triangle index
    int r = (int)((sqrtf(8.0f * p + 1.0f) - 1.0f) * 0.5f);
    while ((r + 1) * (r + 2) / 2 <= p) ++r;
    while (r * (r + 1) / 2 > p) --r;
    const int bi = p - r * (r + 1) / 2;      // I panel (rows of D), bi <= bj
    const int bj = r;                        // J panel (cols of D)
    const int I0 = bi * 128, J0 = bj * 128;
    const bool offdiag = (bi != bj);
    const bool diag = !offdiag;

    const int tid = threadIdx.x;
    const int lane = tid & 63, w = tid >> 6;          // 4 waves
    const int llo = lane & 15, lhi = lane >> 4;
    const int wm = w >> 1, wn = w & 1;                // 2 x 2 wave grid

    __shared__ float epiA[2][128][4];                 // 4 KB
    __shared__ float epiB[2][128][4];                 // 4 KB
    __shared__ int keyI[128];
    __shared__ int keyJ[128];

    if (tid < 128) {
        keyI[tid] = keys[I0 + tid];
        keyJ[tid] = keys[J0 + tid];
    }

    // frag bases: frag index = rowtile*32 + ktile, each frag 1KB contiguous
    const unsigned short* aF = zf + ((size_t)(bi * 8 + wm * 4) * 32) * 512 + lane * 8;
    const unsigned short* bF = zf + ((size_t)(bj * 8 + wn * 4) * 32) * 512 + lane * 8;

    f32x4 acc[4][4];
    #pragma unroll
    for (int m = 0; m < 4; ++m)
        #pragma unroll
        for (int n = 0; n < 4; ++n)
            acc[m][n] = (f32x4){0.f, 0.f, 0.f, 0.f};

    #define LOADF(A, Bf, T)                                                        \
        do {                                                                       \
            _Pragma("unroll")                                                      \
            for (int m = 0; m < 4; ++m)                                            \
                A[m] = *(const bf16x8*)(aF + ((size_t)(m) * 32 + (T)) * 512);      \
            _Pragma("unroll")                                                      \
            for (int n = 0; n < 4; ++n)                                            \
                Bf[n] = *(const bf16x8*)(bF + ((size_t)(n) * 32 + (T)) * 512);     \
        } while (0)

    #define STEP(A, Bf)                                                            \
        do {                                                                       \
            _Pragma("unroll")                                                      \
            for (int m = 0; m < 4; ++m)                                            \
                _Pragma("unroll")                                                  \
                for (int n = 0; n < 4; ++n)                                        \
                    acc[m][n] = __builtin_amdgcn_mfma_f32_16x16x32_bf16(           \
                        A[m], Bf[n], acc[m][n], 0, 0, 0);                          \
        } while (0)

    {
        bf16x8 aC[4], bC[4], aN[4], bN[4];
        LOADF(aC, bC, 0);
        #pragma unroll 1
        for (int t2 = 0; t2 < 16; ++t2) {
            LOADF(aN, bN, 2 * t2 + 1);
            STEP(aC, bC);
            if (t2 < 15) LOADF(aC, bC, 2 * t2 + 2);
            STEP(aN, bN);
        }
    }
    #undef LOADF
    #undef STEP

    __syncthreads();   // keys visible; epi ready

    // -------- dual-sided epilogue ------------------------------------------
    int kJ[4], tcol[4];
    #pragma unroll
    for (int n = 0; n < 4; ++n) {
        tcol[n] = wn * 64 + n * 16 + llo;
        kJ[n] = keyJ[tcol[n]];
    }

    float stB[4][4];
    #pragma unroll
    for (int n = 0; n < 4; ++n)
        #pragma unroll
        for (int s = 0; s < 4; ++s) stB[n][s] = 0.0f;

    #pragma unroll
    for (int m = 0; m < 4; ++m) {
        float stA[4][4];
        #pragma unroll
        for (int rr = 0; rr < 4; ++rr)
            #pragma unroll
            for (int s = 0; s < 4; ++s) stA[rr][s] = 0.0f;

        int kI[4], trow[4];
        #pragma unroll
        for (int rr = 0; rr < 4; ++rr) {
            trow[rr] = wm * 64 + m * 16 + lhi * 4 + rr;
            kI[rr] = keyI[trow[rr]];
        }
        #pragma unroll
        for (int n = 0; n < 4; ++n) {
            #pragma unroll
            for (int rr = 0; rr < 4; ++rr) {
                const float v = acc[m][n][rr] * 10.0f;
                const int x = kI[rr] ^ kJ[n];
                const float pen = (x & 0xFF000000) ? 1.0f : 0.0f;
                const float g = __expf(v - 10.0f - pen);
                if (!(diag && trow[rr] == tcol[n])) {
                    stA[rr][0] += g;           stB[n][0] += g;
                    if ((x & 0xFFFF0000) == 0) { stA[rr][1] += v; stB[n][1] += v; }
                    if ((x & 0xFFFFFF00) == 0) { stA[rr][2] += v; stB[n][2] += v; }
                    if (x == 0)                { stA[rr][3] += v; stB[n][3] += v; }
                }
            }
        }
        // side A: reduce over the 16 llo lanes (cols within wave)
        #pragma unroll
        for (int rr = 0; rr < 4; ++rr)
            #pragma unroll
            for (int s = 0; s < 4; ++s) {
                float vv = stA[rr][s];
                vv += __shfl_xor(vv, 1);
                vv += __shfl_xor(vv, 2);
                vv += __shfl_xor(vv, 4);
                vv += __shfl_xor(vv, 8);
                stA[rr][s] = vv;
            }
        if (llo == 0) {
            #pragma unroll
            for (int rr = 0; rr < 4; ++rr) {
                float4 o; o.x = stA[rr][0]; o.y = stA[rr][1]; o.z = stA[rr][2]; o.w = stA[rr][3];
                *(float4*)&epiA[wn][trow[rr]][0] = o;
            }
        }
    }
    // side B: reduce over the 4 lhi lane-groups (rows within wave)
    #pragma unroll
    for (int n = 0; n < 4; ++n)
        #pragma unroll
        for (int s = 0; s < 4; ++s) {
            float vv = stB[n][s];
            vv += __shfl_xor(vv, 16);
            vv += __shfl_xor(vv, 32);
            stB[n][s] = vv;
        }
    if (lhi == 0) {
        #pragma unroll
        for (int n = 0; n < 4; ++n) {
            float4 o; o.x = stB[n][0]; o.y = stB[n][1]; o.z = stB[n][2]; o.w = stB[n][3];
            *(float4*)&epiB[wm][tcol[n]][0] = o;
        }
    }
    __syncthreads();

    if (tid < 128) {
        const float4 a0 = *(const float4*)&epiA[0][tid][0];
        const float4 a1 = *(const float4*)&epiA[1][tid][0];
        float4 o; o.x = a0.x + a1.x; o.y = a0.y + a1.y; o.z = a0.z + a1.z; o.w = a0.w + a1.w;
        *(float4*)(partials + ((size_t)bj * NB + I0 + tid) * 4) = o;
        if (offdiag) {
            const float4 b0 = *(const float4*)&epiB[0][tid][0];
            const float4 b1 = *(const float4*)&epiB[1][tid][0];
            float4 q; q.x = b0.x + b1.x; q.y = b0.y + b1.y; q.z = b0.z + b1.z; q.w = b0.w + b1.w;
            *(float4*)(partials + ((size_t)bi * NB + J0 + tid) * 4) = q;
        }
    }
}

// ---------------------------------------------------------------------------
// row reduce: block-local LDS histogram of keys (counts), then sum {G,T1,T2,T3}
// over 32 coltiles, per-level per-row values, block-reduce to 6 sums.
// ---------------------------------------------------------------------------
__global__ __launch_bounds__(256) void rowreduce_kernel(
    const float* __restrict__ partials, const int* __restrict__ keys,
    float* __restrict__ blocksums)
{
    const int tid = threadIdx.x;
    const int row = blockIdx.x * 256 + tid;
    const int lane = tid & 63, wid = tid >> 6;

    __shared__ int h3[4096];
    __shared__ int h2[512];
    __shared__ int h1[64];

    for (int i = tid; i < 4096; i += 256) h3[i] = 0;
    __syncthreads();
    for (int i = tid; i < 4096; i += 256) {
        const int k = keys[i];
        const int i3 = (((((k >> 24) & 7) * 8 + ((k >> 16) & 7)) * 8 + ((k >> 8) & 7)) * 8) + (k & 7);
        atomicAdd(&h3[i3], 1);
    }
    __syncthreads();
    for (int i = tid; i < 512; i += 256) {
        int s = 0;
        #pragma unroll
        for (int j = 0; j < 8; ++j) s += h3[i * 8 + j];
        h2[i] = s;
    }
    __syncthreads();
    if (tid < 64) {
        int s = 0;
        #pragma unroll
        for (int j = 0; j < 8; ++j) s += h2[tid * 8 + j];
        h1[tid] = s;
    }
    __syncthreads();

    float G = 0.f, T1 = 0.f, T2 = 0.f, T3 = 0.f;
    for (int ct = 0; ct < 32; ++ct) {
        const float4 u = *(const float4*)(partials + ((size_t)ct * NB + row) * 4);
        G += u.x; T1 += u.y; T2 += u.z; T3 += u.w;
    }
    const float lg = logf(fmaxf(G, 1e-30f)) + 10.0f;   // = logZ + m_i (m_i cancels)

    const int key = keys[row];
    const int i1 = ((key >> 24) & 7) * 8 + ((key >> 16) & 7);
    const int i2 = i1 * 8 + ((key >> 8) & 7);
    const int i3 = i2 * 8 + (key & 7);
    const int C[3] = {h1[i1] - 1, h2[i2] - 1, h3[i3] - 1};
    const float T[3] = {T1, T2, T3};

    float vals[6];
    #pragma unroll
    for (int l = 0; l < 3; ++l) {
        const bool valid = C[l] > 0;
        const float pr = T[l] / fmaxf((float)C[l], 1.0f) - lg;
        vals[2 * l]     = valid ? pr : 0.0f;
        vals[2 * l + 1] = valid ? 1.0f : 0.0f;
    }

    __shared__ float red[4][6];
    #pragma unroll
    for (int s = 0; s < 6; ++s) {
        float v = vals[s];
        #pragma unroll
        for (int o = 32; o > 0; o >>= 1) v += __shfl_xor(v, o);
        vals[s] = v;
    }
    if (lane == 0)
        #pragma unroll
        for (int s = 0; s < 6; ++s) red[wid][s] = vals[s];
    __syncthreads();
    if (tid == 0) {
        #pragma unroll
        for (int s = 0; s < 6; ++s)
            blocksums[blockIdx.x * 8 + s] = red[0][s] + red[1][s] + red[2][s] + red[3][s];
    }
}

// ---------------------------------------------------------------------------
// final: sum 16 block results, run the 3-level scalar loop
// ---------------------------------------------------------------------------
__global__ void final_kernel(const float* __restrict__ blocksums, float* __restrict__ out)
{
    if (threadIdx.x != 0) return;
    float sums[6] = {0, 0, 0, 0, 0, 0};
    for (int b = 0; b < 16; ++b)
        for (int s = 0; s < 6; ++s) sums[s] += blocksums[b * 8 + s];

    const float pen[3] = {2.0f, 1.41421356237309515f, 1.25992104989487319f};
    float total = 0.0f, max_lower = -INFINITY;
    int seen = 0;
    for (int l = 0; l < 3; ++l) {
        const float nv   = sums[2 * l + 1];
        const bool  any  = nv > 0.0f;
        const float mean = sums[2 * l] / fmaxf(nv, 1.0f);
        const float raw  = -mean;                    // TAU/TAU_BASE == 1
        const float lvl  = fmaxf(max_lower, raw);
        if (any) {
            total += lvl * pen[l];
            max_lower = fmaxf(max_lower, lvl);
            seen++;
        }
    }
    out[0] = total / (float)(seen > 0 ? seen : 1);
}

// ---------------------------------------------------------------------------
extern "C" void kernel_launch(void* const* d_in, const int* in_sizes, int n_in,
                              void* d_out, int out_size, void* d_ws, size_t ws_size,
                              hipStream_t stream)
{
    const float* emb    = (const float*)d_in[0];
    const int*   labels = (const int*)d_in[1];
    float*       out    = (float*)d_out;
    char*        ws     = (char*)d_ws;

    // ws layout
    unsigned short* zf    = (unsigned short*)(ws);              // 8388608 B (frag-ordered)
    int*   keys     = (int*)(ws + 8388608);                     // 16384 B
    float* partials = (float*)(ws + 8404992);                   // 2097152 B (32 coltiles)
    float* bsums    = (float*)(ws + 10502144);                  // 512 B

    prep_kernel<<<NB / 4, 256, 0, stream>>>(emb, labels, zf, keys);
    simtile_kernel<<<528, 256, 0, stream>>>(zf, keys, partials);
    rowreduce_kernel<<<NB / 256, 256, 0, stream>>>(partials, keys, bsums);
    final_kernel<<<1, 64, 0, stream>>>(bsums, out);
}

// Round 14
// 49.595 us; speedup vs baseline: 3.0017x; 1.2318x over previous
//
#include <hip/hip_runtime.h>
#include <hip/hip_bf16.h>
#include <stdint.h>

#define NB 4096
#define ND 1024

typedef __attribute__((ext_vector_type(4))) float f32x4;
typedef __attribute__((ext_vector_type(2))) long i64x2;   // 16B = two fp8 MFMA operands

// ---------------------------------------------------------------------------
// prep: row-normalize, quantize to fp8 e4m3 (OCP), write SUPERFRAG-ORDERED zq,
// pack label key. Superfrag sf = rowtile(row/16)*16 + kt64(k/64) is 1KB:
// lane L = (row%16) + 16*((k%32)/8) holds 16B = [k-half0 8B][k-half1 8B]
// (halves = k mod 64 in [0,32) / [32,64)) -- two mfma_16x16x32_fp8 operands.
// Producer lane l (k in [16l,16l+16)): kt64=l>>2, sel=(l>>1)&1, c0=(l&1)*2.
// ---------------------------------------------------------------------------
__global__ __launch_bounds__(256) void prep_kernel(
    const float* __restrict__ emb, const int* __restrict__ labels,
    unsigned char* __restrict__ zq, int* __restrict__ keys)
{
    const int wid = threadIdx.x >> 6, lane = threadIdx.x & 63;
    const int row = blockIdx.x * 4 + wid;
    const float4* src = (const float4*)(emb + (size_t)row * ND) + lane * 4;
    float4 v[4];
    float ss = 0.0f;
    #pragma unroll
    for (int j = 0; j < 4; ++j) {
        v[j] = src[j];
        ss += v[j].x * v[j].x + v[j].y * v[j].y + v[j].z * v[j].z + v[j].w * v[j].w;
    }
    #pragma unroll
    for (int o = 1; o < 64; o <<= 1) ss += __shfl_xor(ss, o);
    const float inv = 1.0f / fmaxf(sqrtf(ss), 1e-12f);

    const float z0 = v[0].x * inv, z1 = v[0].y * inv, z2 = v[0].z * inv, z3 = v[0].w * inv;
    const float z4 = v[1].x * inv, z5 = v[1].y * inv, z6 = v[1].z * inv, z7 = v[1].w * inv;
    const float z8 = v[2].x * inv, z9 = v[2].y * inv, zA = v[2].z * inv, zB = v[2].w * inv;
    const float zC = v[3].x * inv, zD = v[3].y * inv, zE = v[3].z * inv, zF = v[3].w * inv;

    int p0 = 0, p1 = 0, p2 = 0, p3 = 0;
    p0 = __builtin_amdgcn_cvt_pk_fp8_f32(z0, z1, p0, false);
    p0 = __builtin_amdgcn_cvt_pk_fp8_f32(z2, z3, p0, true);
    p1 = __builtin_amdgcn_cvt_pk_fp8_f32(z4, z5, p1, false);
    p1 = __builtin_amdgcn_cvt_pk_fp8_f32(z6, z7, p1, true);
    p2 = __builtin_amdgcn_cvt_pk_fp8_f32(z8, z9, p2, false);
    p2 = __builtin_amdgcn_cvt_pk_fp8_f32(zA, zB, p2, true);
    p3 = __builtin_amdgcn_cvt_pk_fp8_f32(zC, zD, p3, false);
    p3 = __builtin_amdgcn_cvt_pk_fp8_f32(zE, zF, p3, true);

    const int sf  = (row >> 4) * 16 + (lane >> 2);
    const int sel = (lane >> 1) & 1;
    const int c0  = (lane & 1) * 2;
    const int L0  = (row & 15) + 16 * c0;
    unsigned char* d = zq + (size_t)sf * 1024;
    int2 w01; w01.x = p0; w01.y = p1;   // k+0..7  -> chunk c0
    int2 w23; w23.x = p2; w23.y = p3;   // k+8..15 -> chunk c0+1
    *(int2*)(d + L0 * 16 + sel * 8)        = w01;
    *(int2*)(d + (L0 + 16) * 16 + sel * 8) = w23;

    if (lane == 0) {
        const int* lr = labels + row * 4;
        keys[row] = ((lr[3] & 7) << 24) | ((lr[0] & 7) << 16) |
                    ((lr[1] & 7) << 8)  |  (lr[2] & 7);
    }
}

// ---------------------------------------------------------------------------
// simtile: upper-triangle 128x128 tiles of S = Z Z^T / TAU, fp8 direct loads.
// R14: R13 structure (triangle, 528 blocks, 4 waves 2x2 of 64x64, dual-sided
// epilogue, XCD chunking 528=8*66) with fp8 e4m3 operands: per K-64 step,
// 8 dwordx4 loads (HALF of bf16's 16) + 32 mfma_f32_16x16x32_fp8_fp8 (same
// MFMA count as bf16 -- fp8 runs at bf16 rate; we win bytes & instructions:
// R12/R13 measured wall = load bytes/instrs at ~25 B/cy/CU, MfmaUtil 26%).
// zq = 4 MB -> fully L2-resident per XCD. Frags ~160 unified regs -> 12
// waves/CU (3/SIMD, more overlap than R13's ~10).
// ---------------------------------------------------------------------------
__global__ __launch_bounds__(256, 2) void simtile_kernel(
    const unsigned char* __restrict__ zq, const int* __restrict__ keys,
    float* __restrict__ partials)
{
    const int b = blockIdx.x;
    const int p = (b & 7) * 66 + (b >> 3);   // XCD-contiguous triangle index
    int r = (int)((sqrtf(8.0f * p + 1.0f) - 1.0f) * 0.5f);
    while ((r + 1) * (r + 2) / 2 <= p) ++r;
    while (r * (r + 1) / 2 > p) --r;
    const int bi = p - r * (r + 1) / 2;      // I panel (rows of D), bi <= bj
    const int bj = r;                        // J panel (cols of D)
    const int I0 = bi * 128, J0 = bj * 128;
    const bool offdiag = (bi != bj);
    const bool diag = !offdiag;

    const int tid = threadIdx.x;
    const int lane = tid & 63, w = tid >> 6;          // 4 waves
    const int llo = lane & 15, lhi = lane >> 4;
    const int wm = w >> 1, wn = w & 1;                // 2 x 2 wave grid

    __shared__ float epiA[2][128][4];                 // 4 KB
    __shared__ float epiB[2][128][4];                 // 4 KB
    __shared__ int keyI[128];
    __shared__ int keyJ[128];

    if (tid < 128) {
        keyI[tid] = keys[I0 + tid];
        keyJ[tid] = keys[J0 + tid];
    }

    // superfrag bases: rowtile stride 16KB (16 sf x 1KB); t64 stride 1KB
    const unsigned char* aF = zq + (size_t)(bi * 8 + wm * 4) * 16384 + lane * 16;
    const unsigned char* bF = zq + (size_t)(bj * 8 + wn * 4) * 16384 + lane * 16;

    f32x4 acc[4][4];
    #pragma unroll
    for (int m = 0; m < 4; ++m)
        #pragma unroll
        for (int n = 0; n < 4; ++n)
            acc[m][n] = (f32x4){0.f, 0.f, 0.f, 0.f};

    #define LOADF(A, Bf, T)                                                        \
        do {                                                                       \
            _Pragma("unroll")                                                      \
            for (int m = 0; m < 4; ++m)                                            \
                A[m] = *(const i64x2*)(aF + (size_t)(m) * 16384 + (T) * 1024);     \
            _Pragma("unroll")                                                      \
            for (int n = 0; n < 4; ++n)                                            \
                Bf[n] = *(const i64x2*)(bF + (size_t)(n) * 16384 + (T) * 1024);    \
        } while (0)

    #define STEP(A, Bf)                                                            \
        do {                                                                       \
            _Pragma("unroll")                                                      \
            for (int m = 0; m < 4; ++m)                                            \
                _Pragma("unroll")                                                  \
                for (int n = 0; n < 4; ++n) {                                      \
                    acc[m][n] = __builtin_amdgcn_mfma_f32_16x16x32_fp8_fp8(        \
                        A[m][0], Bf[n][0], acc[m][n], 0, 0, 0);                    \
                    acc[m][n] = __builtin_amdgcn_mfma_f32_16x16x32_fp8_fp8(        \
                        A[m][1], Bf[n][1], acc[m][n], 0, 0, 0);                    \
                }                                                                  \
        } while (0)

    {
        i64x2 aC[4], bC[4], aN[4], bN[4];
        LOADF(aC, bC, 0);
        #pragma unroll 1
        for (int t2 = 0; t2 < 8; ++t2) {               // 16 K-64 super-steps
            LOADF(aN, bN, 2 * t2 + 1);
            STEP(aC, bC);
            if (t2 < 7) LOADF(aC, bC, 2 * t2 + 2);
            STEP(aN, bN);
        }
    }
    #undef LOADF
    #undef STEP

    __syncthreads();   // keys visible; epi ready

    // -------- dual-sided epilogue ------------------------------------------
    int kJ[4], tcol[4];
    #pragma unroll
    for (int n = 0; n < 4; ++n) {
        tcol[n] = wn * 64 + n * 16 + llo;
        kJ[n] = keyJ[tcol[n]];
    }

    float stB[4][4];
    #pragma unroll
    for (int n = 0; n < 4; ++n)
        #pragma unroll
        for (int s = 0; s < 4; ++s) stB[n][s] = 0.0f;

    #pragma unroll
    for (int m = 0; m < 4; ++m) {
        float stA[4][4];
        #pragma unroll
        for (int rr = 0; rr < 4; ++rr)
            #pragma unroll
            for (int s = 0; s < 4; ++s) stA[rr][s] = 0.0f;

        int kI[4], trow[4];
        #pragma unroll
        for (int rr = 0; rr < 4; ++rr) {
            trow[rr] = wm * 64 + m * 16 + lhi * 4 + rr;
            kI[rr] = keyI[trow[rr]];
        }
        #pragma unroll
        for (int n = 0; n < 4; ++n) {
            #pragma unroll
            for (int rr = 0; rr < 4; ++rr) {
                const float v = acc[m][n][rr] * 10.0f;
                const int x = kI[rr] ^ kJ[n];
                const float pen = (x & 0xFF000000) ? 1.0f : 0.0f;
                const float g = __expf(v - 10.0f - pen);
                if (!(diag && trow[rr] == tcol[n])) {
                    stA[rr][0] += g;           stB[n][0] += g;
                    if ((x & 0xFFFF0000) == 0) { stA[rr][1] += v; stB[n][1] += v; }
                    if ((x & 0xFFFFFF00) == 0) { stA[rr][2] += v; stB[n][2] += v; }
                    if (x == 0)                { stA[rr][3] += v; stB[n][3] += v; }
                }
            }
        }
        // side A: reduce over the 16 llo lanes (cols within wave)
        #pragma unroll
        for (int rr = 0; rr < 4; ++rr)
            #pragma unroll
            for (int s = 0; s < 4; ++s) {
                float vv = stA[rr][s];
                vv += __shfl_xor(vv, 1);
                vv += __shfl_xor(vv, 2);
                vv += __shfl_xor(vv, 4);
                vv += __shfl_xor(vv, 8);
                stA[rr][s] = vv;
            }
        if (llo == 0) {
            #pragma unroll
            for (int rr = 0; rr < 4; ++rr) {
                float4 o; o.x = stA[rr][0]; o.y = stA[rr][1]; o.z = stA[rr][2]; o.w = stA[rr][3];
                *(float4*)&epiA[wn][trow[rr]][0] = o;
            }
        }
    }
    // side B: reduce over the 4 lhi lane-groups (rows within wave)
    #pragma unroll
    for (int n = 0; n < 4; ++n)
        #pragma unroll
        for (int s = 0; s < 4; ++s) {
            float vv = stB[n][s];
            vv += __shfl_xor(vv, 16);
            vv += __shfl_xor(vv, 32);
            stB[n][s] = vv;
        }
    if (lhi == 0) {
        #pragma unroll
        for (int n = 0; n < 4; ++n) {
            float4 o; o.x = stB[n][0]; o.y = stB[n][1]; o.z = stB[n][2]; o.w = stB[n][3];
            *(float4*)&epiB[wm][tcol[n]][0] = o;
        }
    }
    __syncthreads();

    if (tid < 128) {
        const float4 a0 = *(const float4*)&epiA[0][tid][0];
        const float4 a1 = *(const float4*)&epiA[1][tid][0];
        float4 o; o.x = a0.x + a1.x; o.y = a0.y + a1.y; o.z = a0.z + a1.z; o.w = a0.w + a1.w;
        *(float4*)(partials + ((size_t)bj * NB + I0 + tid) * 4) = o;
        if (offdiag) {
            const float4 b0 = *(const float4*)&epiB[0][tid][0];
            const float4 b1 = *(const float4*)&epiB[1][tid][0];
            float4 q; q.x = b0.x + b1.x; q.y = b0.y + b1.y; q.z = b0.z + b1.z; q.w = b0.w + b1.w;
            *(float4*)(partials + ((size_t)bi * NB + J0 + tid) * 4) = q;
        }
    }
}

// ---------------------------------------------------------------------------
// row reduce: block-local LDS histogram of keys (counts), then sum {G,T1,T2,T3}
// over 32 coltiles, per-level per-row values, block-reduce to 6 sums.
// ---------------------------------------------------------------------------
__global__ __launch_bounds__(256) void rowreduce_kernel(
    const float* __restrict__ partials, const int* __restrict__ keys,
    float* __restrict__ blocksums)
{
    const int tid = threadIdx.x;
    const int row = blockIdx.x * 256 + tid;
    const int lane = tid & 63, wid = tid >> 6;

    __shared__ int h3[4096];
    __shared__ int h2[512];
    __shared__ int h1[64];

    for (int i = tid; i < 4096; i += 256) h3[i] = 0;
    __syncthreads();
    for (int i = tid; i < 4096; i += 256) {
        const int k = keys[i];
        const int i3 = (((((k >> 24) & 7) * 8 + ((k >> 16) & 7)) * 8 + ((k >> 8) & 7)) * 8) + (k & 7);
        atomicAdd(&h3[i3], 1);
    }
    __syncthreads();
    for (int i = tid; i < 512; i += 256) {
        int s = 0;
        #pragma unroll
        for (int j = 0; j < 8; ++j) s += h3[i * 8 + j];
        h2[i] = s;
    }
    __syncthreads();
    if (tid < 64) {
        int s = 0;
        #pragma unroll
        for (int j = 0; j < 8; ++j) s += h2[tid * 8 + j];
        h1[tid] = s;
    }
    __syncthreads();

    float G = 0.f, T1 = 0.f, T2 = 0.f, T3 = 0.f;
    for (int ct = 0; ct < 32; ++ct) {
        const float4 u = *(const float4*)(partials + ((size_t)ct * NB + row) * 4);
        G += u.x; T1 += u.y; T2 += u.z; T3 += u.w;
    }
    const float lg = logf(fmaxf(G, 1e-30f)) + 10.0f;   // = logZ + m_i (m_i cancels)

    const int key = keys[row];
    const int i1 = ((key >> 24) & 7) * 8 + ((key >> 16) & 7);
    const int i2 = i1 * 8 + ((key >> 8) & 7);
    const int i3 = i2 * 8 + (key & 7);
    const int C[3] = {h1[i1] - 1, h2[i2] - 1, h3[i3] - 1};
    const float T[3] = {T1, T2, T3};

    float vals[6];
    #pragma unroll
    for (int l = 0; l < 3; ++l) {
        const bool valid = C[l] > 0;
        const float pr = T[l] / fmaxf((float)C[l], 1.0f) - lg;
        vals[2 * l]     = valid ? pr : 0.0f;
        vals[2 * l + 1] = valid ? 1.0f : 0.0f;
    }

    __shared__ float red[4][6];
    #pragma unroll
    for (int s = 0; s < 6; ++s) {
        float v = vals[s];
        #pragma unroll
        for (int o = 32; o > 0; o >>= 1) v += __shfl_xor(v, o);
        vals[s] = v;
    }
    if (lane == 0)
        #pragma unroll
        for (int s = 0; s < 6; ++s) red[wid][s] = vals[s];
    __syncthreads();
    if (tid == 0) {
        #pragma unroll
        for (int s = 0; s < 6; ++s)
            blocksums[blockIdx.x * 8 + s] = red[0][s] + red[1][s] + red[2][s] + red[3][s];
    }
}

// ---------------------------------------------------------------------------
// final: sum 16 block results, run the 3-level scalar loop
// ---------------------------------------------------------------------------
__global__ void final_kernel(const float* __restrict__ blocksums, float* __restrict__ out)
{
    if (threadIdx.x != 0) return;
    float sums[6] = {0, 0, 0, 0, 0, 0};
    for (int b = 0; b < 16; ++b)
        for (int s = 0; s < 6; ++s) sums[s] += blocksums[b * 8 + s];

    const float pen[3] = {2.0f, 1.41421356237309515f, 1.25992104989487319f};
    float total = 0.0f, max_lower = -INFINITY;
    int seen = 0;
    for (int l = 0; l < 3; ++l) {
        const float nv   = sums[2 * l + 1];
        const bool  any  = nv > 0.0f;
        const float mean = sums[2 * l] / fmaxf(nv, 1.0f);
        const float raw  = -mean;                    // TAU/TAU_BASE == 1
        const float lvl  = fmaxf(max_lower, raw);
        if (any) {
            total += lvl * pen[l];
            max_lower = fmaxf(max_lower, lvl);
            seen++;
        }
    }
    out[0] = total / (float)(seen > 0 ? seen : 1);
}

// ---------------------------------------------------------------------------
extern "C" void kernel_launch(void* const* d_in, const int* in_sizes, int n_in,
                              void* d_out, int out_size, void* d_ws, size_t ws_size,
                              hipStream_t stream)
{
    const float* emb    = (const float*)d_in[0];
    const int*   labels = (const int*)d_in[1];
    float*       out    = (float*)d_out;
    char*        ws     = (char*)d_ws;

    // ws layout
    unsigned char* zq    = (unsigned char*)(ws);                // 4194304 B (fp8 superfrag)
    int*   keys     = (int*)(ws + 4194304);                     // 16384 B
    float* partials = (float*)(ws + 4210688);                   // 2097152 B (32 coltiles)
    float* bsums    = (float*)(ws + 6307840);                   // 512 B

    prep_kernel<<<NB / 4, 256, 0, stream>>>(emb, labels, zq, keys);
    simtile_kernel<<<528, 256, 0, stream>>>(zq, keys, partials);
    rowreduce_kernel<<<NB / 256, 256, 0, stream>>>(partials, keys, bsums);
    final_kernel<<<1, 64, 0, stream>>>(bsums, out);
}